// Round 9
// baseline (1207.185 us; speedup 1.0000x reference)
//
#include <hip/hip_runtime.h>
#include <hip/hip_bf16.h>

typedef __attribute__((ext_vector_type(8))) short bf16x8;
typedef __attribute__((ext_vector_type(4))) float f32x4;

#define GLDS(g, l) \
  __builtin_amdgcn_global_load_lds((const __attribute__((address_space(1))) void*)(g), \
                                   (__attribute__((address_space(3))) void*)(l), 16, 0, 0)

#define MFMA_BF16 __builtin_amdgcn_mfma_f32_16x16x32_bf16

// ---------------- Kernel 1: fused X fp32->bf16 cvt  +  W assembly ----------------
__global__ __launch_bounds__(256) void k_prep(const float* __restrict__ x,
                                              __hip_bfloat16* __restrict__ y,
                                              const float* __restrict__ L,
                                              const float* __restrict__ R,
                                              __hip_bfloat16* __restrict__ W) {
  if (blockIdx.x < 4096) {
    // cvt: grid-stride over 8-element groups
    const long n8 = (long)16384 * 4096 / 8;
    const long stride = (long)4096 * 256;
    for (long i = (long)blockIdx.x * 256 + threadIdx.x; i < n8; i += stride) {
      const float4* xin = reinterpret_cast<const float4*>(x) + i * 2;
      float4 v0 = xin[0];
      float4 v1 = xin[1];
      union { __hip_bfloat16 h[8]; int4 v; } o;
      o.h[0] = __float2bfloat16(v0.x);
      o.h[1] = __float2bfloat16(v0.y);
      o.h[2] = __float2bfloat16(v0.z);
      o.h[3] = __float2bfloat16(v0.w);
      o.h[4] = __float2bfloat16(v1.x);
      o.h[5] = __float2bfloat16(v1.y);
      o.h[6] = __float2bfloat16(v1.z);
      o.h[7] = __float2bfloat16(v1.w);
      *reinterpret_cast<int4*>(y + i * 8) = o.v;
    }
  } else {
    // make_w: one block per (b,c) pair
    const int bc = blockIdx.x - 4096;  // b*64 + c
    const int b = bc >> 6, c = bc & 63;
    const int d = threadIdx.x & 63;
    const int q = threadIdx.x >> 6;
    float Rr[8];
#pragma unroll
    for (int r = 0; r < 8; ++r)
      Rr[r] = R[(((size_t)(r * 64 + b) * 64 + c) << 6) + d];
#pragma unroll 4
    for (int a = q * 16; a < q * 16 + 16; ++a) {
      const float* Lp = L + (((size_t)(a * 64 + b) * 64 + c) << 3);
      float s = 0.f;
#pragma unroll
      for (int r = 0; r < 8; ++r) s = fmaf(Lp[r], Rr[r], s);
      W[((size_t)(a * 64 + b) << 12) + (c << 6) + d] = __float2bfloat16(s);
    }
  }
}

// ---------------- Kernel 2: 256x256 bf16 GEMM; A via LDS, B global->reg ----------
// LDS holds ONLY A (2 x 32KB). B fragments load straight from global (L2/L3-resident W)
// with a 4-phase-deep per-wave counted-vmcnt pipeline (12 loads in flight, never <8).
// A path (staging, swizzle, read-ahead, single barrier per tile) identical to r8.
__global__ __launch_bounds__(512, 2) void k_gemm_bt(const __hip_bfloat16* __restrict__ A,
                                                    const __hip_bfloat16* __restrict__ B,
                                                    const float* __restrict__ bias,
                                                    float* __restrict__ C) {
  const int K = 4096, N = 4096, NT = 64;
  __shared__ char lds[65536];
  char* const sAc = lds;  // 2 x 32768: A tile [256][64] bf16, swizzled

  const int tid = threadIdx.x;
  const int lane = tid & 63;
  const int wid = tid >> 6;
  const int wr = wid >> 2;    // 0..1 (M half)
  const int wc = wid & 3;     // 0..3 (N quarter)

  // T1: bijective XCD swizzle (nwg = 1024, divisible by 8)
  const int orig = blockIdx.x;
  const int wg = (orig & 7) * 128 + (orig >> 3);
  const int gm0 = (wg >> 4) * 256;
  const int gn0 = (wg & 15) * 256;

  // ---- A staging geometry (pre-swizzled global source, linear LDS dest) ----
  const int crow = tid >> 3;
  const int scol = ((tid & 7) << 4) ^ ((crow & 7) << 4);
  const int voff = crow * 8192 + scol;
  const int wbase = (tid >> 6) << 10;
  const char* const Ab = (const char*)(A + (size_t)gm0 * K);

#define STAGEA(BUF, TS)                                                      \
  _Pragma("unroll")                                                          \
  for (int j = 0; j < 4; ++j)                                                \
    GLDS(Ab + (size_t)((TS) * 128 + j * 524288) + voff,                      \
         sAc + (BUF) * 32768 + j * 8192 + wbase);

  // ---- A fragment-read geometry (swizzled ds_read) ----
  const int lr = lane & 15;
  const int lk = lane >> 4;
  const int kx0 = (lk << 4) ^ ((lr & 7) << 4);
  const int kx1 = (64 + (lk << 4)) ^ ((lr & 7) << 4);
  const char* const rA0 = sAc + (((wr << 7) + lr) << 7) + kx0;
  const char* const rA1 = sAc + (((wr << 7) + lr) << 7) + kx1;

#define PREFA(DST, BUF, MOFS)                                                \
  _Pragma("unroll")                                                          \
  for (int m = 0; m < 4; ++m) {                                              \
    DST[m][0] = *(const bf16x8*)(rA0 + (BUF) * 32768 + ((MOFS) + m) * 2048); \
    DST[m][1] = *(const bf16x8*)(rA1 + (BUF) * 32768 + ((MOFS) + m) * 2048); \
  }

  // ---- B direct-from-global geometry ----
  // fragment (n, kxh): 16B at row gn0+wc*64+n*16+lr, byte kt*128 + lk*16 + kxh*64
  const char* const Bq = (const char*)(B + (size_t)gn0 * K) +
                         (size_t)((wc << 6) + lr) * 8192 + (lk << 4);

#define LOADB01K0(BN, TB)                                                    \
  BN##01[0][0] = *(const bf16x8*)(Bq + (size_t)(TB) * 128);                  \
  BN##01[1][0] = *(const bf16x8*)(Bq + 131072 + (size_t)(TB) * 128);
#define LOADB01K1(BN, TB)                                                    \
  BN##01[0][1] = *(const bf16x8*)(Bq + (size_t)(TB) * 128 + 64);             \
  BN##01[1][1] = *(const bf16x8*)(Bq + 131072 + (size_t)(TB) * 128 + 64);
#define LOADB23K0(BN, TB)                                                    \
  BN##23[0][0] = *(const bf16x8*)(Bq + 262144 + (size_t)(TB) * 128);         \
  BN##23[1][0] = *(const bf16x8*)(Bq + 393216 + (size_t)(TB) * 128);
#define LOADB23K1(BN, TB)                                                    \
  BN##23[0][1] = *(const bf16x8*)(Bq + 262144 + (size_t)(TB) * 128 + 64);    \
  BN##23[1][1] = *(const bf16x8*)(Bq + 393216 + (size_t)(TB) * 128 + 64);

#define MFMA8X(AF, BF, MB, NB)                                               \
  _Pragma("unroll")                                                          \
  for (int m = 0; m < 4; ++m) {                                              \
    acc[(MB) + m][(NB) + 0] =                                                \
        MFMA_BF16(AF[m][0], BF[0][0], acc[(MB) + m][(NB) + 0], 0, 0, 0);     \
    acc[(MB) + m][(NB) + 0] =                                                \
        MFMA_BF16(AF[m][1], BF[0][1], acc[(MB) + m][(NB) + 0], 0, 0, 0);     \
    acc[(MB) + m][(NB) + 1] =                                                \
        MFMA_BF16(AF[m][0], BF[1][0], acc[(MB) + m][(NB) + 1], 0, 0, 0);     \
    acc[(MB) + m][(NB) + 1] =                                                \
        MFMA_BF16(AF[m][1], BF[1][1], acc[(MB) + m][(NB) + 1], 0, 0, 0);     \
  }

#define LGKM0 asm volatile("s_waitcnt lgkmcnt(0)" ::: "memory")
#define SBAR0 __builtin_amdgcn_sched_barrier(0)
#define VMC(N) asm volatile("s_waitcnt vmcnt(" #N ")" ::: "memory")

  // epilogue coords (needed for bias-seeded acc)
  const int er = gm0 + (wr << 7) + ((lane >> 4) << 2);
  const int ec = gn0 + (wc << 6) + (lane & 15);

  f32x4 acc[8][4];
#pragma unroll
  for (int n = 0; n < 4; ++n) {
    const float bv = bias[ec + n * 16];
#pragma unroll
    for (int m = 0; m < 8; ++m) acc[m][n] = (f32x4){bv, bv, bv, bv};
  }

  bf16x8 aX[4][2], aY[4][2];
  bf16x8 bA01[2][2], bA23[2][2], bB01[2][2], bB23[2][2];

  // ---- prologue (issue order matters for the vmcnt ledger) ----
  STAGEA(0, 0)                          // A(0): 4
  LOADB01K0(bA, 0) LOADB01K1(bA, 0)     // b01(0): 4
  STAGEA(1, 1)                          // A(1): 4
  LOADB23K0(bA, 0) LOADB23K1(bA, 0)     // b23(0): 4
  VMC(12);                              // drain A(0); leaves [b01(0),A(1),b23(0)] = 12
  SBAR0;
  __builtin_amdgcn_s_barrier();
  PREFA(aX, 0, 0)

  // Ledger (steady, oldest->newest entering P1): b01(t)4 | A(t+1)4 | b23(t)4 = 12
  //   P1: vmcnt(8)  -> b01(t) ready (issued 4 phases ago)
  //   P3 pre-barrier: vmcnt(8) -> A(t+1) certified (cross-wave publish)
  //   P3 post: vmcnt(10) -> b23(t) ready
#define TILE(BUF, BC, BN, T)                                                 \
  {                                                                          \
    const int tS = ((T) + 2 < NT) ? (T) + 2 : NT - 1;                        \
    const int tB = ((T) + 1 < NT) ? (T) + 1 : NT - 1;                        \
    /* P1: Q1 = aX x Bn01 */                                                 \
    VMC(8); SBAR0;                                                           \
    LGKM0; SBAR0;                                                            \
    PREFA(aY, BUF, 4)                                                        \
    LOADB01K0(BN, tB)                                                        \
    SBAR0;                                                                   \
    __builtin_amdgcn_s_setprio(1);                                           \
    MFMA8X(aX, BC##01, 0, 0)                                                 \
    __builtin_amdgcn_s_setprio(0);                                           \
    /* P2: Q2 = aY x Bn01 */                                                 \
    LGKM0; SBAR0;                                                            \
    LOADB01K1(BN, tB)                                                        \
    SBAR0;                                                                   \
    __builtin_amdgcn_s_setprio(1);                                           \
    MFMA8X(aY, BC##01, 4, 0)                                                 \
    __builtin_amdgcn_s_setprio(0);                                           \
    /* P3: certify A(t+1) PRE-barrier; stage A(t+2); Q3 = aX x Bn23 */       \
    VMC(8); SBAR0;                                                           \
    __builtin_amdgcn_s_barrier();                                            \
    STAGEA(BUF, tS)                                                          \
    LOADB23K0(BN, tB)                                                        \
    VMC(10); SBAR0;                                                          \
    __builtin_amdgcn_s_setprio(1);                                           \
    MFMA8X(aX, BC##23, 0, 2)                                                 \
    __builtin_amdgcn_s_setprio(0);                                           \
    /* P4: Q4 = aY x Bn23 */                                                 \
    SBAR0;                                                                   \
    PREFA(aX, (BUF) ^ 1, 0)                                                  \
    LOADB23K1(BN, tB)                                                        \
    SBAR0;                                                                   \
    __builtin_amdgcn_s_setprio(1);                                           \
    MFMA8X(aY, BC##23, 4, 2)                                                 \
    __builtin_amdgcn_s_setprio(0);                                           \
  }

  for (int t = 0; t < NT; t += 2) {
    TILE(0, bA, bB, t)
    TILE(1, bB, bA, t + 1)
  }
  asm volatile("s_waitcnt vmcnt(0) lgkmcnt(0)" ::: "memory");

  // ---- epilogue: C[row][col] = acc (bias pre-seeded) ----
#pragma unroll
  for (int n = 0; n < 4; ++n) {
    const int c = ec + n * 16;
#pragma unroll
    for (int m = 0; m < 8; ++m) {
#pragma unroll
      for (int j = 0; j < 4; ++j) {
        C[(size_t)(er + m * 16 + j) * N + c] = acc[m][n][j];
      }
    }
  }
}

extern "C" void kernel_launch(void* const* d_in, const int* in_sizes, int n_in,
                              void* d_out, int out_size, void* d_ws, size_t ws_size,
                              hipStream_t stream) {
  const float* x = (const float*)d_in[0];     // [8,2048,4096]
  const float* L = (const float*)d_in[1];     // [64,64,64,8]
  const float* R = (const float*)d_in[2];     // [8,64,64,64]
  const float* bias = (const float*)d_in[3];  // [4096]
  float* out = (float*)d_out;                 // [16384,4096]

  __hip_bfloat16* Wb = (__hip_bfloat16*)d_ws;                                    // 33.5 MB
  __hip_bfloat16* Xb = (__hip_bfloat16*)((char*)d_ws + (size_t)4096 * 4096 * 2); // 134 MB

  k_prep<<<8192, 256, 0, stream>>>(x, Xb, L, R, Wb);

  dim3 grid(1024);  // (16384/256) * (4096/256)
  k_gemm_bt<<<grid, 512, 0, stream>>>(Xb, Wb, bias, out);
}

// Round 10
// 718.360 us; speedup vs baseline: 1.6805x; 1.6805x over previous
//
#include <hip/hip_runtime.h>
#include <hip/hip_bf16.h>

typedef __attribute__((ext_vector_type(8))) short bf16x8;
typedef __attribute__((ext_vector_type(4))) float f32x4;

#define GLDS(g, l) \
  __builtin_amdgcn_global_load_lds((const __attribute__((address_space(1))) void*)(g), \
                                   (__attribute__((address_space(3))) void*)(l), 16, 0, 0)

#define MFMA_BF16 __builtin_amdgcn_mfma_f32_16x16x32_bf16

// ---------------- Kernel 1: fused X fp32->bf16 cvt + W assembly (fragment-order W2) ----
// W2 layout: byte = ((n16*64 + kt)*2 + kxh)*1024 + (lr*4 + lk)*16 + e*2
//   holds W[row = n16*16 + lr][k = kt*64 + kxh*32 + lk*8 + e]
// -> GEMM B-fragment load = one contiguous 1KB per wave (perfect coalescing).
__global__ __launch_bounds__(256) void k_prep(const float* __restrict__ x,
                                              __hip_bfloat16* __restrict__ y,
                                              const float* __restrict__ L,
                                              const float* __restrict__ R,
                                              char* __restrict__ W2) {
  if (blockIdx.x < 4096) {
    const long n8 = (long)16384 * 4096 / 8;
    const long stride = (long)4096 * 256;
    for (long i = (long)blockIdx.x * 256 + threadIdx.x; i < n8; i += stride) {
      const float4* xin = reinterpret_cast<const float4*>(x) + i * 2;
      float4 v0 = xin[0];
      float4 v1 = xin[1];
      union { __hip_bfloat16 h[8]; int4 v; } o;
      o.h[0] = __float2bfloat16(v0.x);
      o.h[1] = __float2bfloat16(v0.y);
      o.h[2] = __float2bfloat16(v0.z);
      o.h[3] = __float2bfloat16(v0.w);
      o.h[4] = __float2bfloat16(v1.x);
      o.h[5] = __float2bfloat16(v1.y);
      o.h[6] = __float2bfloat16(v1.z);
      o.h[7] = __float2bfloat16(v1.w);
      *reinterpret_cast<int4*>(y + i * 8) = o.v;
    }
  } else {
    const int bc = blockIdx.x - 4096;  // b*64 + c
    const int b = bc >> 6, c = bc & 63;
    const int d = threadIdx.x & 63;
    const int q = threadIdx.x >> 6;
    const int kxh = d >> 5, lk = (d >> 3) & 3, e = d & 7;
    const int lr = b & 15;
    const int sub = ((lr << 2) + lk) * 16 + e * 2 + kxh * 1024;
    float Rr[8];
#pragma unroll
    for (int r = 0; r < 8; ++r)
      Rr[r] = R[(((size_t)(r * 64 + b) * 64 + c) << 6) + d];
#pragma unroll 4
    for (int a = q * 16; a < q * 16 + 16; ++a) {
      const float* Lp = L + (((size_t)(a * 64 + b) * 64 + c) << 3);
      float s = 0.f;
#pragma unroll
      for (int r = 0; r < 8; ++r) s = fmaf(Lp[r], Rr[r], s);
      const int n16 = (a << 2) + (b >> 4);
      *(__hip_bfloat16*)(W2 + ((size_t)(n16 * 64 + c) << 11) + sub) = __float2bfloat16(s);
    }
  }
}

// ---------------- Kernel 2: 256x256 bf16 GEMM; A via LDS (r8 path), B global->reg -----
// LDS = A only (2 x 32 KB). B fragments load from fragment-order W2: 1KB coalesced
// per wave per fragment-pair, compiler-tracked waits. One manual vmcnt(4) pre-barrier
// per tile certifies A(t+1) gload_lds (cross-wave). Registers == r8 (no spill).
__global__ __launch_bounds__(512, 2) void k_gemm_bt(const __hip_bfloat16* __restrict__ A,
                                                    const char* __restrict__ B2,
                                                    const float* __restrict__ bias,
                                                    float* __restrict__ C) {
  const int K = 4096, N = 4096, NT = 64;
  __shared__ char lds[65536];
  char* const sAc = lds;  // 2 x 32768: A tile [256][64] bf16, swizzled

  const int tid = threadIdx.x;
  const int lane = tid & 63;
  const int wid = tid >> 6;
  const int wr = wid >> 2;    // 0..1 (M half)
  const int wc = wid & 3;     // 0..3 (N quarter)

  // T1: bijective XCD swizzle (nwg = 1024, divisible by 8)
  const int orig = blockIdx.x;
  const int wg = (orig & 7) * 128 + (orig >> 3);
  const int gm0 = (wg >> 4) * 256;
  const int gn0 = (wg & 15) * 256;

  // ---- A staging geometry (pre-swizzled global source, linear LDS dest; == r8) ----
  const int crow = tid >> 3;
  const int scol = ((tid & 7) << 4) ^ ((crow & 7) << 4);
  const int voff = crow * 8192 + scol;
  const int wbase = (tid >> 6) << 10;
  const char* const Ab = (const char*)(A + (size_t)gm0 * K);

#define STAGEA(BUF, TS)                                                      \
  _Pragma("unroll")                                                          \
  for (int j = 0; j < 4; ++j)                                                \
    GLDS(Ab + (size_t)((TS) * 128 + j * 524288) + voff,                      \
         sAc + (BUF) * 32768 + j * 8192 + wbase);

  // ---- A fragment-read geometry (swizzled ds_read; == r8) ----
  const int lr = lane & 15;
  const int lk = lane >> 4;
  const int kx0 = (lk << 4) ^ ((lr & 7) << 4);
  const int kx1 = (64 + (lk << 4)) ^ ((lr & 7) << 4);
  const char* const rA0 = sAc + (((wr << 7) + lr) << 7) + kx0;
  const char* const rA1 = sAc + (((wr << 7) + lr) << 7) + kx1;

#define PREFA(DST, BUF, MOFS)                                                \
  _Pragma("unroll")                                                          \
  for (int m = 0; m < 4; ++m) {                                              \
    DST[m][0] = *(const bf16x8*)(rA0 + (BUF) * 32768 + ((MOFS) + m) * 2048); \
    DST[m][1] = *(const bf16x8*)(rA1 + (BUF) * 32768 + ((MOFS) + m) * 2048); \
  }

  // ---- B fragment-order global geometry ----
  // fragment (n, kxh) of tile t: 1KB block at ((n16b+n)*64 + t)*2048 + kxh*1024,
  // lane chunk = (lr*4 + lk)*16  (per-thread constant, folded into base)
  const char* const Bq2 = B2 + (size_t)((gn0 >> 4) + (wc << 2)) * 131072 +
                          (((lr << 2) + lk) << 4);

#define LOADBPAIR(BN, TB, NOFS)                                                         \
  BN[0][0] = *(const bf16x8*)(Bq2 + (size_t)(NOFS)*131072 + (size_t)(TB)*2048);         \
  BN[0][1] = *(const bf16x8*)(Bq2 + (size_t)(NOFS)*131072 + (size_t)(TB)*2048 + 1024);  \
  BN[1][0] = *(const bf16x8*)(Bq2 + (size_t)((NOFS)+1)*131072 + (size_t)(TB)*2048);     \
  BN[1][1] = *(const bf16x8*)(Bq2 + (size_t)((NOFS)+1)*131072 + (size_t)(TB)*2048 + 1024);

#define MFMA8X(AF, BF, MB, NB)                                               \
  _Pragma("unroll")                                                          \
  for (int m = 0; m < 4; ++m) {                                              \
    acc[(MB) + m][(NB) + 0] =                                                \
        MFMA_BF16(AF[m][0], BF[0][0], acc[(MB) + m][(NB) + 0], 0, 0, 0);     \
    acc[(MB) + m][(NB) + 0] =                                                \
        MFMA_BF16(AF[m][1], BF[0][1], acc[(MB) + m][(NB) + 0], 0, 0, 0);     \
    acc[(MB) + m][(NB) + 1] =                                                \
        MFMA_BF16(AF[m][0], BF[1][0], acc[(MB) + m][(NB) + 1], 0, 0, 0);     \
    acc[(MB) + m][(NB) + 1] =                                                \
        MFMA_BF16(AF[m][1], BF[1][1], acc[(MB) + m][(NB) + 1], 0, 0, 0);     \
  }

#define LGKM0 asm volatile("s_waitcnt lgkmcnt(0)" ::: "memory")
#define SBAR0 __builtin_amdgcn_sched_barrier(0)
#define VMC(Nn) asm volatile("s_waitcnt vmcnt(" #Nn ")" ::: "memory")

  const int er = gm0 + (wr << 7) + ((lane >> 4) << 2);
  const int ec = gn0 + (wc << 6) + (lane & 15);

  f32x4 acc[8][4];
#pragma unroll
  for (int n = 0; n < 4; ++n) {
    const float bv = bias[ec + n * 16];
#pragma unroll
    for (int m = 0; m < 8; ++m) acc[m][n] = (f32x4){bv, bv, bv, bv};
  }

  bf16x8 aX[4][2], aY[4][2], b0[2][2], b2[2][2];

  // ---- prologue: A(0)[4], B01(0)[4], A(1)[4]; drain A(0) only ----
  STAGEA(0, 0)
  LOADBPAIR(b0, 0, 0)
  STAGEA(1, 1)
  VMC(8);  // A(0) landed; [b0(0), A(1)] = 8 in flight
  SBAR0;
  __builtin_amdgcn_s_barrier();
  PREFA(aX, 0, 0)

  // Steady ledger (outstanding at P1 entry, oldest->newest): b0(t)4 | A(t+1)4
  //   P1: issue B23(t); compiler waits b0 (vmcnt(8)) before MFMA
  //   P3: VMC(4) pre-barrier -> A(t+1) certified (4-phase HBM cover); barrier;
  //       issue B01(t+1) then A(t+2); compiler waits b2 (vmcnt(8)) before MFMA
#define TILE(BUF, T)                                                         \
  {                                                                          \
    const int tS = ((T) + 2 < NT) ? (T) + 2 : NT - 1;                        \
    const int tB = ((T) + 1 < NT) ? (T) + 1 : NT - 1;                        \
    /* P1: Q1 = aX x b0 */                                                   \
    LGKM0; SBAR0;                                                            \
    PREFA(aY, BUF, 4)                                                        \
    LOADBPAIR(b2, T, 2)                                                      \
    SBAR0;                                                                   \
    __builtin_amdgcn_s_setprio(1);                                           \
    MFMA8X(aX, b0, 0, 0)                                                     \
    __builtin_amdgcn_s_setprio(0);                                           \
    /* P2: Q2 = aY x b0 */                                                   \
    LGKM0; SBAR0;                                                            \
    __builtin_amdgcn_s_setprio(1);                                           \
    MFMA8X(aY, b0, 4, 0)                                                     \
    __builtin_amdgcn_s_setprio(0);                                           \
    /* P3: certify A(t+1) PRE-barrier; stage next; Q3 = aX x b2 */           \
    VMC(4); SBAR0;                                                           \
    __builtin_amdgcn_s_barrier();                                            \
    LOADBPAIR(b0, tB, 0)                                                     \
    STAGEA(BUF, tS)                                                          \
    SBAR0;                                                                   \
    __builtin_amdgcn_s_setprio(1);                                           \
    MFMA8X(aX, b2, 0, 2)                                                     \
    __builtin_amdgcn_s_setprio(0);                                           \
    /* P4: Q4 = aY x b2 */                                                   \
    PREFA(aX, (BUF) ^ 1, 0)                                                  \
    SBAR0;                                                                   \
    __builtin_amdgcn_s_setprio(1);                                           \
    MFMA8X(aY, b2, 4, 2)                                                     \
    __builtin_amdgcn_s_setprio(0);                                           \
  }

  for (int t = 0; t < NT; t += 2) {
    TILE(0, t)
    TILE(1, t + 1)
  }
  asm volatile("s_waitcnt vmcnt(0) lgkmcnt(0)" ::: "memory");

  // ---- epilogue: C[row][col] = acc (bias pre-seeded) ----
#pragma unroll
  for (int n = 0; n < 4; ++n) {
    const int c = ec + n * 16;
#pragma unroll
    for (int m = 0; m < 8; ++m) {
#pragma unroll
      for (int j = 0; j < 4; ++j) {
        C[(size_t)(er + m * 16 + j) * N + c] = acc[m][n][j];
      }
    }
  }
}

extern "C" void kernel_launch(void* const* d_in, const int* in_sizes, int n_in,
                              void* d_out, int out_size, void* d_ws, size_t ws_size,
                              hipStream_t stream) {
  const float* x = (const float*)d_in[0];     // [8,2048,4096]
  const float* L = (const float*)d_in[1];     // [64,64,64,8]
  const float* R = (const float*)d_in[2];     // [8,64,64,64]
  const float* bias = (const float*)d_in[3];  // [4096]
  float* out = (float*)d_out;                 // [16384,4096]

  char* W2 = (char*)d_ws;                                                        // 33.5 MB
  __hip_bfloat16* Xb = (__hip_bfloat16*)((char*)d_ws + (size_t)4096 * 4096 * 2); // 134 MB

  k_prep<<<8192, 256, 0, stream>>>(x, Xb, L, R, W2);

  dim3 grid(1024);  // (16384/256) * (4096/256)
  k_gemm_bt<<<grid, 512, 0, stream>>>(Xb, W2, bias, out);
}

// Round 12
// 569.692 us; speedup vs baseline: 2.1190x; 1.2610x over previous
//
#include <hip/hip_runtime.h>
#include <hip/hip_bf16.h>

typedef __attribute__((ext_vector_type(8))) short bf16x8;
typedef __attribute__((ext_vector_type(4))) float f32x4;

#define GLDS(g, l) \
  __builtin_amdgcn_global_load_lds((const __attribute__((address_space(1))) void*)(g), \
                                   (__attribute__((address_space(3))) void*)(l), 16, 0, 0)

#define MFMA_BF16 __builtin_amdgcn_mfma_f32_16x16x32_bf16

// ---------------- Kernel 1: X fp32 -> bf16 (r8-proven) ----------------
__global__ __launch_bounds__(256) void k_cvt_bf16(const float* __restrict__ x,
                                                  __hip_bfloat16* __restrict__ y,
                                                  long n8) {
  long stride = (long)gridDim.x * blockDim.x;
  for (long i = (long)blockIdx.x * blockDim.x + threadIdx.x; i < n8; i += stride) {
    const float4* xin = reinterpret_cast<const float4*>(x) + i * 2;
    float4 v0 = xin[0];
    float4 v1 = xin[1];
    union { __hip_bfloat16 h[8]; int4 v; } o;
    o.h[0] = __float2bfloat16(v0.x);
    o.h[1] = __float2bfloat16(v0.y);
    o.h[2] = __float2bfloat16(v0.z);
    o.h[3] = __float2bfloat16(v0.w);
    o.h[4] = __float2bfloat16(v1.x);
    o.h[5] = __float2bfloat16(v1.y);
    o.h[6] = __float2bfloat16(v1.z);
    o.h[7] = __float2bfloat16(v1.w);
    *reinterpret_cast<int4*>(y + i * 8) = o.v;
  }
}

// ---------------- Kernel 2: assemble W bf16 (r8-proven, low-traffic) ----------------
__global__ __launch_bounds__(256) void k_make_w(const float* __restrict__ L,
                                                const float* __restrict__ R,
                                                __hip_bfloat16* __restrict__ W) {
  const int bc = blockIdx.x;  // b*64 + c
  const int b = bc >> 6, c = bc & 63;
  const int d = threadIdx.x & 63;
  const int q = threadIdx.x >> 6;
  float Rr[8];
#pragma unroll
  for (int r = 0; r < 8; ++r)
    Rr[r] = R[(((size_t)(r * 64 + b) * 64 + c) << 6) + d];
#pragma unroll 4
  for (int a = q * 16; a < q * 16 + 16; ++a) {
    const float* Lp = L + (((size_t)(a * 64 + b) * 64 + c) << 3);
    float s = 0.f;
#pragma unroll
    for (int r = 0; r < 8; ++r) s = fmaf(Lp[r], Rr[r], s);
    W[((size_t)(a * 64 + b) << 12) + (c << 6) + d] = __float2bfloat16(s);
  }
}

// ---------------- Kernel 3: 256x256 bf16 GEMM — fence-free phases, explicit boundary --
// r8 structure (tiles/swizzle/staging/read-ahead/bias-seed) with intra-phase manual
// fences REMOVED (compiler emits counted lgkmcnt interleave; ds_read->MFMA deps are
// register-visible). Tile boundary keeps r8's EXPLICIT pre-barrier drain:
//   asm lgkmcnt(0) vmcnt(0) [memory] ; sched_barrier ; s_barrier ; sched_barrier
// (r11 lesson: __syncthreads does NOT drain vmcnt for global_load_lds on this
// toolchain; r5/r6 lesson: the drain must be BEFORE the barrier.)
__global__ __launch_bounds__(512, 2) void k_gemm_bt(const __hip_bfloat16* __restrict__ A,
                                                    const __hip_bfloat16* __restrict__ B,
                                                    const float* __restrict__ bias,
                                                    float* __restrict__ C) {
  const int K = 4096, N = 4096, NT = 64;
  __shared__ char lds[131072];
  char* const sAc = lds;          // 2 x 32768: A tile [256][64] bf16, swizzled
  char* const sBc = lds + 65536;  // 2 x 32768

  const int tid = threadIdx.x;
  const int lane = tid & 63;
  const int wid = tid >> 6;
  const int wr = wid >> 2;    // 0..1 (M half)
  const int wc = wid & 3;     // 0..3 (N quarter)

  // T1: bijective XCD swizzle (nwg = 1024, divisible by 8)
  const int orig = blockIdx.x;
  const int wg = (orig & 7) * 128 + (orig >> 3);
  const int gm0 = (wg >> 4) * 256;
  const int gn0 = (wg & 15) * 256;

  // ---- staging geometry (pre-swizzled global source, linear LDS dest) ----
  const int crow = tid >> 3;
  const int scol = ((tid & 7) << 4) ^ ((crow & 7) << 4);
  const int voff = crow * 8192 + scol;
  const int wbase = (tid >> 6) << 10;
  const char* const Ab = (const char*)(A + (size_t)gm0 * K);
  const char* const Bb = (const char*)(B + (size_t)gn0 * K);

#define STAGEA(BUF, TS)                                                      \
  _Pragma("unroll")                                                          \
  for (int j = 0; j < 4; ++j)                                                \
    GLDS(Ab + (size_t)((TS) * 128 + j * 524288) + voff,                      \
         sAc + (BUF) * 32768 + j * 8192 + wbase);

#define STAGEB(BUF, TS)                                                      \
  _Pragma("unroll")                                                          \
  for (int j = 0; j < 4; ++j)                                                \
    GLDS(Bb + (size_t)((TS) * 128 + j * 524288) + voff,                      \
         sBc + (BUF) * 32768 + j * 8192 + wbase);

  // ---- fragment-read geometry (swizzled ds_read) ----
  const int lr = lane & 15;
  const int lk = lane >> 4;
  const int kx0 = (lk << 4) ^ ((lr & 7) << 4);
  const int kx1 = (64 + (lk << 4)) ^ ((lr & 7) << 4);
  const char* const rA0 = sAc + (((wr << 7) + lr) << 7) + kx0;
  const char* const rA1 = sAc + (((wr << 7) + lr) << 7) + kx1;
  const char* const rB0 = sBc + (((wc << 6) + lr) << 7) + kx0;
  const char* const rB1 = sBc + (((wc << 6) + lr) << 7) + kx1;

#define PREFA(DST, BUF, MOFS)                                                \
  _Pragma("unroll")                                                          \
  for (int m = 0; m < 4; ++m) {                                              \
    DST[m][0] = *(const bf16x8*)(rA0 + (BUF) * 32768 + ((MOFS) + m) * 2048); \
    DST[m][1] = *(const bf16x8*)(rA1 + (BUF) * 32768 + ((MOFS) + m) * 2048); \
  }

#define PREFB(DST, BUF, NOFS)                                                \
  _Pragma("unroll")                                                          \
  for (int n = 0; n < 2; ++n) {                                              \
    DST[n][0] = *(const bf16x8*)(rB0 + (BUF) * 32768 + ((NOFS) + n) * 2048); \
    DST[n][1] = *(const bf16x8*)(rB1 + (BUF) * 32768 + ((NOFS) + n) * 2048); \
  }

#define MFMA8X(AF, BF, MB, NB)                                               \
  _Pragma("unroll")                                                          \
  for (int m = 0; m < 4; ++m) {                                              \
    acc[(MB) + m][(NB) + 0] =                                                \
        MFMA_BF16(AF[m][0], BF[0][0], acc[(MB) + m][(NB) + 0], 0, 0, 0);     \
    acc[(MB) + m][(NB) + 0] =                                                \
        MFMA_BF16(AF[m][1], BF[0][1], acc[(MB) + m][(NB) + 0], 0, 0, 0);     \
    acc[(MB) + m][(NB) + 1] =                                                \
        MFMA_BF16(AF[m][0], BF[1][0], acc[(MB) + m][(NB) + 1], 0, 0, 0);     \
    acc[(MB) + m][(NB) + 1] =                                                \
        MFMA_BF16(AF[m][1], BF[1][1], acc[(MB) + m][(NB) + 1], 0, 0, 0);     \
  }

#define SBAR0 __builtin_amdgcn_sched_barrier(0)
// Tile boundary: certify (per-wave drain of ALL lds reads + ALL vmem incl
// global_load_lds) BEFORE s_barrier; sched_barrier brackets pin the optimizer.
#define TILE_SYNC                                                            \
  asm volatile("s_waitcnt lgkmcnt(0) vmcnt(0)" ::: "memory");                \
  SBAR0;                                                                     \
  __builtin_amdgcn_s_barrier();                                              \
  SBAR0;

  // epilogue coords (needed for bias-seeded acc)
  const int er = gm0 + (wr << 7) + ((lane >> 4) << 2);
  const int ec = gn0 + (wc << 6) + (lane & 15);

  f32x4 acc[8][4];
#pragma unroll
  for (int n = 0; n < 4; ++n) {
    const float bv = bias[ec + n * 16];
#pragma unroll
    for (int m = 0; m < 8; ++m) acc[m][n] = (f32x4){bv, bv, bv, bv};
  }

  bf16x8 aX[4][2], aY[4][2], b0[2][2], b2[2][2];

  // ---- prologue: stage tiles 0,1; explicit drain of tile 0; publish; first reads ----
  STAGEA(0, 0) STAGEB(0, 0) STAGEA(1, 1) STAGEB(1, 1)
  asm volatile("s_waitcnt vmcnt(8)" ::: "memory");
  SBAR0;
  __builtin_amdgcn_s_barrier();
  SBAR0;
  PREFA(aX, 0, 0) PREFB(b0, 0, 0)

  // Phase order per tile: P1(m03,n01,aX) P2(m47,n01,aY) P3(m03,n23,aX) P4(m47,n23,aY)
  // Prefetch: P1->aY=A47(t)  P2->b2=B23(t)  P3->b0=B01(t+1)  P4->aX=A03(t+1)
  // Staging:  P3: A(t+2)->BUF (post-sync);  P4: B(t+2)->BUF
  // Intra-phase: NO manual fences — compiler emits counted lgkmcnt for the
  // register-visible ds_read->MFMA deps and interleaves reads under MFMA.
#define TILE(BUF, T)                                                         \
  {                                                                          \
    const int tS = ((T) + 2 < NT) ? (T) + 2 : NT - 1;                        \
    /* P1 */                                                                 \
    PREFA(aY, BUF, 4)                                                        \
    __builtin_amdgcn_s_setprio(1);                                           \
    MFMA8X(aX, b0, 0, 0)                                                     \
    __builtin_amdgcn_s_setprio(0);                                           \
    /* P2 */                                                                 \
    PREFB(b2, BUF, 2)                                                        \
    __builtin_amdgcn_s_setprio(1);                                           \
    MFMA8X(aY, b0, 4, 0)                                                     \
    __builtin_amdgcn_s_setprio(0);                                           \
    /* P3: tile boundary (explicit certify-then-publish) */                  \
    TILE_SYNC                                                                \
    STAGEA(BUF, tS)                                                          \
    PREFB(b0, (BUF) ^ 1, 0)                                                  \
    __builtin_amdgcn_s_setprio(1);                                           \
    MFMA8X(aX, b2, 0, 2)                                                     \
    __builtin_amdgcn_s_setprio(0);                                           \
    /* P4 */                                                                 \
    STAGEB(BUF, tS)                                                          \
    PREFA(aX, (BUF) ^ 1, 0)                                                  \
    __builtin_amdgcn_s_setprio(1);                                           \
    MFMA8X(aY, b2, 4, 2)                                                     \
    __builtin_amdgcn_s_setprio(0);                                           \
  }

  for (int t = 0; t < NT; t += 2) {
    TILE(0, t)
    TILE(1, t + 1)
  }
  asm volatile("s_waitcnt vmcnt(0) lgkmcnt(0)" ::: "memory");

  // ---- epilogue: C[row][col] = acc (bias pre-seeded) ----
#pragma unroll
  for (int n = 0; n < 4; ++n) {
    const int c = ec + n * 16;
#pragma unroll
    for (int m = 0; m < 8; ++m) {
#pragma unroll
      for (int j = 0; j < 4; ++j) {
        C[(size_t)(er + m * 16 + j) * N + c] = acc[m][n][j];
      }
    }
  }
}

extern "C" void kernel_launch(void* const* d_in, const int* in_sizes, int n_in,
                              void* d_out, int out_size, void* d_ws, size_t ws_size,
                              hipStream_t stream) {
  const float* x = (const float*)d_in[0];     // [8,2048,4096]
  const float* L = (const float*)d_in[1];     // [64,64,64,8]
  const float* R = (const float*)d_in[2];     // [8,64,64,64]
  const float* bias = (const float*)d_in[3];  // [4096]
  float* out = (float*)d_out;                 // [16384,4096]

  __hip_bfloat16* Wb = (__hip_bfloat16*)d_ws;                                    // 33.5 MB
  __hip_bfloat16* Xb = (__hip_bfloat16*)((char*)d_ws + (size_t)4096 * 4096 * 2); // 134 MB

  const long n8 = (long)16384 * 4096 / 8;
  k_cvt_bf16<<<4096, 256, 0, stream>>>(x, Xb, n8);
  k_make_w<<<4096, 256, 0, stream>>>(L, R, Wb);

  dim3 grid(1024);  // (16384/256) * (4096/256)
  k_gemm_bt<<<grid, 512, 0, stream>>>(Xb, Wb, bias, out);
}